// Round 1
// baseline (362.905 us; speedup 1.0000x reference)
//
#include <hip/hip_runtime.h>

// Problem: y = relu(x @ (w1*m)^T + b1) @ (w2*m^T)^T + b2
// x:[131072,256] f32, w1:[1024,256], b1:[1024], w2:[256,1024], b2:[256], mask:[1024,256] i32
// Fused over hidden chunks of 32; bf16 MFMA 16x16x32; weights pre-swizzled to B-frag order.

#define D_MODEL 256
#define D_HID   1024
#define MT      64      // rows per block
#define CHUNK   32      // hidden units per chunk
#define NCHUNK  (D_HID / CHUNK)   // 32
#define CHUNK_ELEMS 8192          // 32*256 bf16 elems per chunk (16 KB)

typedef __attribute__((ext_vector_type(8))) short short8;
typedef __attribute__((ext_vector_type(4))) float v4f;

__device__ __forceinline__ unsigned short f2bf(float f) {
  union { float f; unsigned int u; } v; v.f = f;
  unsigned int u = v.u;
  return (unsigned short)((u + 0x7FFFu + ((u >> 16) & 1u)) >> 16);  // RNE
}

__device__ __forceinline__ void async16(void* lds, const void* g) {
  __builtin_amdgcn_global_load_lds(
      (const __attribute__((address_space(1))) unsigned int*)g,
      (__attribute__((address_space(3))) unsigned int*)lds,
      16, 0, 0);
}

// ---------------- prep: mask+cast+swizzle weights into B-frag order ----------
// W1p slot s = ((c*8+kk)*2+nf)*64+lane holds W1eff[h=c*32+nf*16+(lane&15)][k=kk*32+(lane>>4)*8 + j], j=0..7
// W2p slot s = (c*16+nf2)*64+lane    holds W2eff[n=nf2*16+(lane&15)][h=c*32+(lane>>4)*8 + j]
__global__ __launch_bounds__(256) void prep_weights(
    const float* __restrict__ w1, const float* __restrict__ w2,
    const int* __restrict__ mask,
    unsigned short* __restrict__ W1p, unsigned short* __restrict__ W2p)
{
  int t = blockIdx.x * 256 + threadIdx.x;   // 0..65535
  if (t < 32768) {
    int c    = t >> 10;
    int kk   = (t >> 7) & 7;
    int nf   = (t >> 6) & 1;
    int lane = t & 63;
    int h = c * 32 + nf * 16 + (lane & 15);
    int k = kk * 32 + (lane >> 4) * 8;
    const float* wp = w1 + h * 256 + k;
    const int*   mp = mask + h * 256 + k;
    short8 v;
    #pragma unroll
    for (int j = 0; j < 8; ++j) v[j] = (short)(mp[j] ? f2bf(wp[j]) : 0);
    *(short8*)(W1p + (size_t)t * 8) = v;
  } else {
    int s    = t - 32768;
    int c    = s >> 10;
    int nf2  = (s >> 6) & 15;
    int lane = s & 63;
    int n = nf2 * 16 + (lane & 15);
    int h = c * 32 + (lane >> 4) * 8;
    const float* wp = w2 + n * 1024 + h;
    short8 v;
    #pragma unroll
    for (int j = 0; j < 8; ++j)
      v[j] = (short)(mask[(h + j) * 256 + n] ? f2bf(wp[j]) : 0);
    *(short8*)(W2p + (size_t)s * 8) = v;
  }
}

// ---------------- fused main kernel ----------------
__global__ __launch_bounds__(256, 3) void ffd_fused(
    const float* __restrict__ X, const float* __restrict__ b1,
    const float* __restrict__ b2,
    const unsigned short* __restrict__ W1p, const unsigned short* __restrict__ W2p,
    float* __restrict__ Y)
{
  __shared__ unsigned short sW1[CHUNK_ELEMS];   // 16 KB, B-frag order
  __shared__ unsigned short sW2[CHUNK_ELEMS];   // 16 KB, B-frag order
  __shared__ unsigned short sHc[4][16 * 48];    // per-wave [row][48] (pad for b128-aligned rows)

  const int tid  = threadIdx.x;
  const int lane = tid & 63;
  const int w    = tid >> 6;
  const int l16  = lane & 15;
  const int q    = lane >> 4;

  const long rowBase = (long)blockIdx.x * MT + w * 16 + l16;

  // X A-fragments (full K=256) in registers: xf[kk][j] = X[row][kk*32 + q*8 + j]
  short8 xf[8];
  const float* xrow = X + rowBase * D_MODEL;
  #pragma unroll
  for (int kk = 0; kk < 8; ++kk) {
    const float4 f0 = *(const float4*)(xrow + kk * 32 + q * 8);
    const float4 f1 = *(const float4*)(xrow + kk * 32 + q * 8 + 4);
    short8 v;
    v[0] = (short)f2bf(f0.x); v[1] = (short)f2bf(f0.y);
    v[2] = (short)f2bf(f0.z); v[3] = (short)f2bf(f0.w);
    v[4] = (short)f2bf(f1.x); v[5] = (short)f2bf(f1.y);
    v[6] = (short)f2bf(f1.z); v[7] = (short)f2bf(f1.w);
    xf[kk] = v;
  }

  v4f acc[16];
  #pragma unroll
  for (int i = 0; i < 16; ++i) acc[i] = (v4f){0.f, 0.f, 0.f, 0.f};

  unsigned short* sHw = sHc[w];

  for (int c = 0; c < NCHUNK; ++c) {
    __syncthreads();   // all waves done reading sW1/sW2 of previous chunk
    {
      const unsigned short* g1 = W1p + (size_t)c * CHUNK_ELEMS + tid * 8;
      const unsigned short* g2 = W2p + (size_t)c * CHUNK_ELEMS + tid * 8;
      #pragma unroll
      for (int i = 0; i < 4; ++i) {
        async16(&sW1[i * 2048 + tid * 8], g1 + i * 2048);
        async16(&sW2[i * 2048 + tid * 8], g2 + i * 2048);
      }
    }
    const float bb0 = b1[c * 32 + l16];
    const float bb1 = b1[c * 32 + 16 + l16];
    __syncthreads();   // staging complete (vmcnt(0) drained by compiler before barrier)

    // fc1: Hc[16 rows (this wave)][32 hidden] = X(regs) @ W1c^T
    v4f h0 = {0.f, 0.f, 0.f, 0.f}, h1 = {0.f, 0.f, 0.f, 0.f};
    #pragma unroll
    for (int kk = 0; kk < 8; ++kk) {
      short8 bf0 = *(const short8*)&sW1[(kk * 2 + 0) * 512 + lane * 8];
      short8 bf1 = *(const short8*)&sW1[(kk * 2 + 1) * 512 + lane * 8];
      h0 = __builtin_amdgcn_mfma_f32_16x16x32_bf16(xf[kk], bf0, h0, 0, 0, 0);
      h1 = __builtin_amdgcn_mfma_f32_16x16x32_bf16(xf[kk], bf1, h1, 0, 0, 0);
    }

    // bias + relu, C-layout -> row-major bf16 scratch (wave-private, no barrier)
    #pragma unroll
    for (int r = 0; r < 4; ++r) {
      float v0 = h0[r] + bb0; v0 = v0 > 0.f ? v0 : 0.f;
      float v1 = h1[r] + bb1; v1 = v1 > 0.f ? v1 : 0.f;
      int row = q * 4 + r;
      sHw[row * 48 + l16]      = f2bf(v0);
      sHw[row * 48 + 16 + l16] = f2bf(v1);
    }
    __threadfence_block();   // order ds_write -> ds_read within the wave

    // fc2: acc[16 rows][256 cols] += Hc @ W2c^T   (K = 32 = one MFMA step)
    short8 af = *(const short8*)&sHw[l16 * 48 + q * 8];
    #pragma unroll
    for (int nf2 = 0; nf2 < 16; ++nf2) {
      short8 bf2 = *(const short8*)&sW2[nf2 * 512 + lane * 8];
      acc[nf2] = __builtin_amdgcn_mfma_f32_16x16x32_bf16(af, bf2, acc[nf2], 0, 0, 0);
    }
  }

  // epilogue: + b2, store fp32
  const long orow = (long)blockIdx.x * MT + w * 16;
  #pragma unroll
  for (int nf2 = 0; nf2 < 16; ++nf2) {
    int col = nf2 * 16 + l16;
    float bias = b2[col];
    #pragma unroll
    for (int r = 0; r < 4; ++r) {
      long row = orow + q * 4 + r;
      Y[row * D_MODEL + col] = acc[nf2][r] + bias;
    }
  }
}

extern "C" void kernel_launch(void* const* d_in, const int* in_sizes, int n_in,
                              void* d_out, int out_size, void* d_ws, size_t ws_size,
                              hipStream_t stream) {
  const float* x    = (const float*)d_in[0];
  const float* w1   = (const float*)d_in[1];
  const float* b1   = (const float*)d_in[2];
  const float* w2   = (const float*)d_in[3];
  const float* b2   = (const float*)d_in[4];
  const int*   mask = (const int*)d_in[5];

  unsigned short* W1p = (unsigned short*)d_ws;          // 512 KB
  unsigned short* W2p = W1p + (size_t)D_HID * D_MODEL;  // 512 KB
  float* Y = (float*)d_out;

  prep_weights<<<256, 256, 0, stream>>>(w1, w2, mask, W1p, W2p);
  ffd_fused<<<131072 / MT, 256, 0, stream>>>(x, b1, b2, W1p, W2p, Y);
}